// Round 7
// baseline (68560.919 us; speedup 1.0000x reference)
//
#include <hip/hip_runtime.h>

#define T_LEN 131072
#define HDIM  100
#define KPAD  112            // 100 h | 5 x | 1 bias-one | 6 zero
#define NTHR  448
#define LOG2E 1.4426950408889634f

typedef __attribute__((ext_vector_type(2))) float f32x2;

// Layout: 448 threads = 7 waves. Quad j (lanes 4j..4j+3) owns hidden unit j
// (j<100 active). Lane g owns K-slice cols [28g, 28g+28) of the augmented
// K = [h(100) | x(5) | 1 | pad6]. Weights: 4 gate-rows x 28 cols = 112 floats
// per thread held in 56 INDIVIDUALLY-NAMED f32x2 registers (arrays provoke
// compiler rematerialization/spill: R1 VGPR=96, R4=140, R6=80; named vars
// stayed resident in R3 at VGPR=224). Rows pre-scaled by log2e (2log2e for
// tanh row) so nonlinearities are raw exp2. Per step: 7 ds_read_b128,
// 56 v_pk_fma_f32, 2-step quad DPP butterfly, local replicated cell update,
// lane0 writes h, lanes<5 write x_{t+1}, ONE barrier (double-buffered LDS).

template <int PAT>
__device__ __forceinline__ float qdpp(float v) {
    return __int_as_float(__builtin_amdgcn_mov_dpp(__float_as_int(v), PAT, 0xf, 0xf, true));
}

__global__ __launch_bounds__(NTHR, 1)
void lstm_seq_kernel(const float* __restrict__ input_seq,
                     const float* __restrict__ W_ih,
                     const float* __restrict__ W_hh,
                     const float* __restrict__ b_ih,
                     const float* __restrict__ b_hh,
                     const float* __restrict__ W_lin,
                     const float* __restrict__ b_lin,
                     float* __restrict__ out)
{
    __shared__ __align__(16) float hbuf[2][KPAD];

    const int tid = threadIdx.x;
    const int j   = tid >> 2;            // quad id / hidden index 0..111
    const int g   = tid & 3;             // K-slice id
    const bool act = j < HDIM;
    const int je  = act ? j : 0;
    const int cb  = 28 * g;              // first col of this lane's slice

    // one augmented, pre-scaled weight element: row, col in [0,112)
    auto wcol = [&](int row, int col, float sc) -> float {
        float wv;
        if      (col < HDIM)      wv = W_hh[row * HDIM + col];
        else if (col < HDIM + 5)  wv = W_ih[row * 5 + (col - HDIM)];
        else if (col == HDIM + 5) wv = b_ih[row] + b_hh[row];
        else                      wv = 0.f;
        return wv * sc;
    };

    const int r0 = je, r1 = HDIM + je, r2 = 2 * HDIM + je, r3 = 3 * HDIM + je;
    const float s1 = LOG2E, s2 = 2.f * LOG2E;

    // ---- 56 named f32x2 weight registers ----
#define WD(v, r, sc, k) const f32x2 w##v##_##k = f32x2{ wcol(r, cb + 2*(k), sc), wcol(r, cb + 2*(k) + 1, sc) };
#define WROW(v, r, sc) \
    WD(v,r,sc,0)  WD(v,r,sc,1)  WD(v,r,sc,2)  WD(v,r,sc,3)  WD(v,r,sc,4)  \
    WD(v,r,sc,5)  WD(v,r,sc,6)  WD(v,r,sc,7)  WD(v,r,sc,8)  WD(v,r,sc,9)  \
    WD(v,r,sc,10) WD(v,r,sc,11) WD(v,r,sc,12) WD(v,r,sc,13)
    WROW(0, r0, s1) WROW(1, r1, s1) WROW(2, r2, s2) WROW(3, r3, s1)
#undef WROW
#undef WD

    // ---- init LDS: h=0 both buffers, x_0 in buf0, bias-one in both ----
    if (tid < 2 * KPAD) ((float*)hbuf)[tid] = 0.f;
    __syncthreads();
    if (tid < 5) hbuf[0][HDIM + tid] = input_seq[tid];
    if (tid == 5) { hbuf[0][HDIM + 5] = 1.f; hbuf[1][HDIM + 5] = 1.f; }
    __syncthreads();

    float c = 0.f;                       // cell state, replicated in the quad

    for (int t = 0; t < T_LEN; ++t) {
        // prefetch next x (5 lanes), latency hidden under the matvec
        float xn = 0.f;
        if (tid < 5) {
            const int tn = (t + 1 < T_LEN) ? (t + 1) : (T_LEN - 1);
            xn = input_seq[tn * 5 + tid];
        }

        // h-slice: 7 x ds_read_b128 (4 distinct 16B segments per wave -> conflict-free)
        const float4* __restrict__ hp = (const float4*)(hbuf[t & 1] + cb);
        const float4 q0 = hp[0], q1 = hp[1], q2 = hp[2], q3 = hp[3];
        const float4 q4 = hp[4], q5 = hp[5], q6 = hp[6];

        // 4 gate-row partials, 8 accumulators (ILP), packed fp32 fma
        f32x2 p0a = f32x2{0.f, 0.f}, p0b = f32x2{0.f, 0.f};
        f32x2 p1a = f32x2{0.f, 0.f}, p1b = f32x2{0.f, 0.f};
        f32x2 p2a = f32x2{0.f, 0.f}, p2b = f32x2{0.f, 0.f};
        f32x2 p3a = f32x2{0.f, 0.f}, p3b = f32x2{0.f, 0.f};
#define FMQ(Q, KA, KB) {                                  \
        const f32x2 hA = f32x2{Q.x, Q.y};                 \
        const f32x2 hB = f32x2{Q.z, Q.w};                 \
        p0a = hA * w0_##KA + p0a;  p0b = hB * w0_##KB + p0b; \
        p1a = hA * w1_##KA + p1a;  p1b = hB * w1_##KB + p1b; \
        p2a = hA * w2_##KA + p2a;  p2b = hB * w2_##KB + p2b; \
        p3a = hA * w3_##KA + p3a;  p3b = hB * w3_##KB + p3b; }
        FMQ(q0, 0, 1)  FMQ(q1, 2, 3)  FMQ(q2, 4, 5)  FMQ(q3, 6, 7)
        FMQ(q4, 8, 9)  FMQ(q5, 10, 11) FMQ(q6, 12, 13)
#undef FMQ
        float p0 = (p0a.x + p0a.y) + (p0b.x + p0b.y);
        float p1 = (p1a.x + p1a.y) + (p1b.x + p1b.y);
        float p2 = (p2a.x + p2a.y) + (p2b.x + p2b.y);
        float p3 = (p3a.x + p3a.y) + (p3b.x + p3b.y);

        // quad butterfly: after xor1+xor2 every lane holds full z0..z3
        p0 += qdpp<0xB1>(p0); p1 += qdpp<0xB1>(p1);   // quad_perm(1,0,3,2)
        p2 += qdpp<0xB1>(p2); p3 += qdpp<0xB1>(p3);
        p0 += qdpp<0x4E>(p0); p1 += qdpp<0x4E>(p1);   // quad_perm(2,3,0,1)
        p2 += qdpp<0x4E>(p2); p3 += qdpp<0x4E>(p3);

        // gates (rows pre-scaled: sigmoid rows by log2e, tanh row by 2log2e)
        const float si = __builtin_amdgcn_rcpf(1.f + __builtin_amdgcn_exp2f(-p0));
        const float sf = __builtin_amdgcn_rcpf(1.f + __builtin_amdgcn_exp2f(-p1));
        const float gg = fmaf(2.f, __builtin_amdgcn_rcpf(1.f + __builtin_amdgcn_exp2f(-p2)), -1.f);
        const float so = __builtin_amdgcn_rcpf(1.f + __builtin_amdgcn_exp2f(-p3));

        // cell update (replicated across the quad's 4 lanes)
        c = fmaf(sf, c, si * gg);
        const float th = fmaf(2.f, __builtin_amdgcn_rcpf(1.f + __builtin_amdgcn_exp2f(c * (-2.f * LOG2E))), -1.f);
        const float hv = so * th;

        float* __restrict__ hn = hbuf[(t + 1) & 1];
        if ((g == 0) & act) hn[j] = hv;
        if (tid < 5) hn[HDIM + tid] = xn;
        __syncthreads();                 // single barrier per step
    }

    // epilogue: out = b_lin + W_lin . h_T   (T_LEN even -> h_T in hbuf[0])
    if (tid == 0) {
        float acc = b_lin[0];
        #pragma unroll
        for (int k = 0; k < HDIM; ++k) acc += W_lin[k] * hbuf[0][k];
        out[0] = acc;
    }
}

extern "C" void kernel_launch(void* const* d_in, const int* in_sizes, int n_in,
                              void* d_out, int out_size, void* d_ws, size_t ws_size,
                              hipStream_t stream) {
    const float* input_seq = (const float*)d_in[0];
    const float* W_ih      = (const float*)d_in[1];
    const float* W_hh      = (const float*)d_in[2];
    const float* b_ih      = (const float*)d_in[3];
    const float* b_hh      = (const float*)d_in[4];
    const float* W_lin     = (const float*)d_in[5];
    const float* b_lin     = (const float*)d_in[6];
    float* out = (float*)d_out;

    lstm_seq_kernel<<<1, NTHR, 0, stream>>>(input_seq, W_ih, W_hh, b_ih, b_hh,
                                            W_lin, b_lin, out);
}